// Round 9
// baseline (174.425 us; speedup 1.0000x reference)
//
#include <hip/hip_runtime.h>
#include <math.h>

// LinearAttention: out[n,l,h,m] = (phi(Q[l])·KV[:,m]) / (phi(Q[l])·Ksum + eps)
//   KV[d][m] = sum_s phi(K[s,d]) V[s,m],  Ksum[d] = sum_s phi(K[s,d])
//   phi(x) = elu(x)+1 = x>0 ? x+1 : exp(x)

#define N_B 8
#define S_LEN 8192
#define H_N 8
#define D_DIM 64
#define NH (N_B * H_N)
#define EPS 1e-6f
#define ROWSTRIDE (H_N * D_DIM)   // 512 floats between consecutive s rows
#define NCHUNK 32
#define CROWS (S_LEN / NCHUNK)    // 256 s-rows per block
#define TS 32                     // s-rows per LDS tile
#define TILES (CROWS / TS)        // 8

typedef __attribute__((ext_vector_type(8)))  __bf16 bf16x8;
typedef __attribute__((ext_vector_type(4)))  float  f32x4;
typedef __attribute__((ext_vector_type(4)))  int    i32x4;
typedef __attribute__((ext_vector_type(2)))  int    i32x2;

__device__ __forceinline__ float felu1(float x) {
    return x > 0.0f ? x + 1.0f : __expf(x);
}
__device__ __forceinline__ unsigned bfb(float f) {
    __bf16 h = (__bf16)f;                       // RNE convert
    return (unsigned)__builtin_bit_cast(unsigned short, h);
}
__device__ __forceinline__ int pack2bf(float a, float b) {
    return (int)(bfb(a) | (bfb(b) << 16));
}

// ---------------- Phase 1a: contiguous-read MFMA KV partial ----------------
// Block = (n, chunk): reads 256 s-rows x ALL 8 heads (fully sequential HBM).
// 8 waves; wave w owns head w. LDS: bf16 tiles in [4s][16d] subtiles; MFMA
// A/B frags fetched with ds_read_b64_tr_b16 (HW transpose). Ksum via B=ones
// MFMA. Double-buffered LDS, reg-staged loads (T14), 1 barrier/tile.
__global__ __launch_bounds__(512, 2) void kv_partial_kernel(
        const float* __restrict__ Kin, const float* __restrict__ Vin,
        float* __restrict__ kvp,   // [NH*NCHUNK][64*64]
        float* __restrict__ ksp) { // [NH*NCHUNK][64]
    __shared__ __align__(16) __bf16 KL[2][16384];  // 32 KB each buffer
    __shared__ __align__(16) __bf16 VL[2][16384];

    const int b   = blockIdx.x;          // 0..255
    const int n_i = b >> 5;
    const int c   = b & 31;
    const int s0  = c * CROWS;

    const int t = threadIdx.x;           // 0..511
    const int w = t >> 6;                // wave = head 0..7
    const int l = t & 63;

    const float* Kb = Kin + (size_t)n_i * S_LEN * ROWSTRIDE;
    const float* Vb = Vin + (size_t)n_i * S_LEN * ROWSTRIDE;

    // staging role: row srow (0..31), cols [scg*32, scg*32+32)
    const int srow = t >> 4;
    const int scg  = t & 15;
    // LDS write byte offsets: subtile (db*8 + s_subtile)*128 + (s&3)*32
    const int wr0 = ((scg * 2 + 0) * 8 + (srow >> 2)) * 128 + (srow & 3) * 32;
    const int wr1 = ((scg * 2 + 1) * 8 + (srow >> 2)) * 128 + (srow & 3) * 32;

    float4 kr[8], vr[8];                 // in-flight staging registers

    auto issue = [&](int tile) {
        const size_t base = (size_t)(s0 + tile * TS + srow) * ROWSTRIDE + scg * 32;
        #pragma unroll
        for (int i = 0; i < 8; ++i) {
            kr[i] = *(const float4*)(Kb + base + i * 4);
            vr[i] = *(const float4*)(Vb + base + i * 4);
        }
    };

    auto convwrite = [&](int buf) {
        int kp[16], vp[16];
        #pragma unroll
        for (int i = 0; i < 8; ++i) {
            kp[2 * i]     = pack2bf(felu1(kr[i].x), felu1(kr[i].y));
            kp[2 * i + 1] = pack2bf(felu1(kr[i].z), felu1(kr[i].w));
            vp[2 * i]     = pack2bf(vr[i].x, vr[i].y);
            vp[2 * i + 1] = pack2bf(vr[i].z, vr[i].w);
        }
        char* kb = (char*)&KL[buf][0];
        char* vb = (char*)&VL[buf][0];
        *(i32x4*)(kb + wr0)      = (i32x4){kp[0], kp[1], kp[2], kp[3]};
        *(i32x4*)(kb + wr0 + 16) = (i32x4){kp[4], kp[5], kp[6], kp[7]};
        *(i32x4*)(kb + wr1)      = (i32x4){kp[8], kp[9], kp[10], kp[11]};
        *(i32x4*)(kb + wr1 + 16) = (i32x4){kp[12], kp[13], kp[14], kp[15]};
        *(i32x4*)(vb + wr0)      = (i32x4){vp[0], vp[1], vp[2], vp[3]};
        *(i32x4*)(vb + wr0 + 16) = (i32x4){vp[4], vp[5], vp[6], vp[7]};
        *(i32x4*)(vb + wr1)      = (i32x4){vp[8], vp[9], vp[10], vp[11]};
        *(i32x4*)(vb + wr1 + 16) = (i32x4){vp[12], vp[13], vp[14], vp[15]};
    };

    f32x4 kvacc[4][4];
    f32x4 ksacc[4];
    #pragma unroll
    for (int i = 0; i < 4; ++i) {
        ksacc[i] = (f32x4){0.f, 0.f, 0.f, 0.f};
        #pragma unroll
        for (int j = 0; j < 4; ++j) kvacc[i][j] = (f32x4){0.f, 0.f, 0.f, 0.f};
    }
    const bf16x8 ONES = __builtin_bit_cast(bf16x8,
        (i32x4){0x3F803F80, 0x3F803F80, 0x3F803F80, 0x3F803F80});

    // per-lane tr-read offset: contiguous b64 within 16-lane group; group g
    // reads s-subtile 2g (+128B for 2g+1). Frag db for head w, tile dt: 4w+dt.
    const int rdlane = (l & 15) * 8 + (l >> 4) * 256;

    auto compute = [&](int buf) {
        unsigned kbase, vbase;
        {
            auto kp3 = (__attribute__((address_space(3))) char*)&KL[buf][0];
            auto vp3 = (__attribute__((address_space(3))) char*)&VL[buf][0];
            kbase = (unsigned)(size_t)kp3 + rdlane;
            vbase = (unsigned)(size_t)vp3 + rdlane;
        }
        bf16x8 A[4], B[4];
        #pragma unroll
        for (int dt = 0; dt < 4; ++dt) {
            const unsigned ka = kbase + (4 * w + dt) * 1024;
            const unsigned va = vbase + (4 * w + dt) * 1024;
            i32x2 r1, r2, r3, r4;
            asm volatile("ds_read_b64_tr_b16 %0, %2\n\t"
                         "ds_read_b64_tr_b16 %1, %2 offset:128"
                         : "=&v"(r1), "=&v"(r2) : "v"(ka));
            asm volatile("ds_read_b64_tr_b16 %0, %2\n\t"
                         "ds_read_b64_tr_b16 %1, %2 offset:128"
                         : "=&v"(r3), "=&v"(r4) : "v"(va));
            A[dt] = __builtin_bit_cast(bf16x8, (i32x4){r1.x, r1.y, r2.x, r2.y});
            B[dt] = __builtin_bit_cast(bf16x8, (i32x4){r3.x, r3.y, r4.x, r4.y});
        }
        asm volatile("s_waitcnt lgkmcnt(0)" ::: "memory");
        __builtin_amdgcn_sched_barrier(0);
        #pragma unroll
        for (int dt = 0; dt < 4; ++dt) {
            ksacc[dt] = __builtin_amdgcn_mfma_f32_16x16x32_bf16(
                            A[dt], ONES, ksacc[dt], 0, 0, 0);
            #pragma unroll
            for (int mt = 0; mt < 4; ++mt)
                kvacc[dt][mt] = __builtin_amdgcn_mfma_f32_16x16x32_bf16(
                                    A[dt], B[mt], kvacc[dt][mt], 0, 0, 0);
        }
    };

    // pipeline: stage 0, prefetch 1, then per tile {compute, conv t+1, issue t+2}
    issue(0);
    convwrite(0);
    issue(1);
    __syncthreads();

    for (int tile = 0; tile < TILES; ++tile) {
        const int cur = tile & 1;
        compute(cur);
        if (tile + 1 < TILES) convwrite(cur ^ 1);
        if (tile + 2 < TILES) issue(tile + 2);
        __syncthreads();
    }

    // ---- write this head's partial KV + Ksum ----
    const size_t ob = (size_t)(n_i * H_N + w) * NCHUNK + c;
    float* kvo = kvp + ob * (D_DIM * D_DIM);
    #pragma unroll
    for (int dt = 0; dt < 4; ++dt) {
        #pragma unroll
        for (int mt = 0; mt < 4; ++mt) {
            #pragma unroll
            for (int r = 0; r < 4; ++r) {
                const int row = dt * 16 + (l >> 4) * 4 + r;  // d
                const int col = mt * 16 + (l & 15);          // m
                kvo[row * 64 + col] = kvacc[dt][mt][r];
            }
        }
    }
    if ((l & 15) == 0) {
        #pragma unroll
        for (int dt = 0; dt < 4; ++dt)
            #pragma unroll
            for (int r = 0; r < 4; ++r)
                ksp[ob * D_DIM + dt * 16 + (l >> 4) * 4 + r] = ksacc[dt][r];
    }
}

// ---------------- Phase 1b: reduce partials -> final KV, Ksum ----------------
__global__ __launch_bounds__(256) void kv_reduce_kernel(
        const float* __restrict__ kvp, const float* __restrict__ ksp,
        float* __restrict__ KV, float* __restrict__ Ksum) {
    const int nh = blockIdx.x >> 4;
    const int eb = blockIdx.x & 15;
    const int t  = threadIdx.x;
    const int e  = eb * 256 + t;
    float s = 0.0f;
    const float* base = kvp + (size_t)nh * NCHUNK * (D_DIM * D_DIM) + e;
    #pragma unroll 8
    for (int c = 0; c < NCHUNK; ++c)
        s += base[(size_t)c * (D_DIM * D_DIM)];
    KV[(size_t)nh * (D_DIM * D_DIM) + e] = s;
    if (eb == 0 && t < D_DIM) {
        float ks = 0.0f;
        #pragma unroll 8
        for (int c = 0; c < NCHUNK; ++c)
            ks += ksp[(size_t)nh * NCHUNK * D_DIM + (size_t)c * D_DIM + t];
        Ksum[(size_t)nh * D_DIM + t] = ks;
    }
}

// ---------------- Phase 2: out = (Q·KV) / (Q·Ksum + eps) ----------------
// Grid remap: b = ((n*nblk + rb) * 8) + h (R8, kept).
__global__ __launch_bounds__(256) void out_kernel(
        const float* __restrict__ Qin, const float* __restrict__ KV,
        const float* __restrict__ Ksum, float* __restrict__ Out) {
    constexpr int RPB  = 128;
    constexpr int QPAD = 68;
    __shared__ __align__(16) float KVs[D_DIM][D_DIM];   // 16 KB
    __shared__ __align__(16) float Kss[D_DIM];
    __shared__ __align__(16) float Qs[RPB][QPAD];       // 34.8 KB, XOR-swizzled cols

    const int b    = blockIdx.x;
    const int nblk = S_LEN / RPB;          // 64
    const int h_i  = b & 7;
    const int rest = b >> 3;
    const int rb   = rest & (nblk - 1);
    const int n_i  = rest >> 6;            // nblk = 64
    const int nh   = n_i * H_N + h_i;
    const int t    = threadIdx.x;

    const float* Qb = Qin + (size_t)n_i * S_LEN * ROWSTRIDE + (size_t)h_i * D_DIM;
    float*       Ob = Out + (size_t)n_i * S_LEN * ROWSTRIDE + (size_t)h_i * D_DIM;

    {
        const float4* src = (const float4*)(KV + (size_t)nh * (D_DIM * D_DIM));
        float4* dst = (float4*)(&KVs[0][0]);
        #pragma unroll
        for (int i = 0; i < 4; ++i) dst[t + 256 * i] = src[t + 256 * i];
        if (t < 16) ((float4*)Kss)[t] = ((const float4*)(Ksum + (size_t)nh * D_DIM))[t];
    }

    const int ltx = t & 15, lty = t >> 4;
    const int sbase = rb * RPB;
    #pragma unroll
    for (int i = 0; i < 8; ++i) {
        const int row = lty + 16 * i;
        const float4 q = *(const float4*)(Qb + (size_t)(sbase + row) * ROWSTRIDE + ltx * 4);
        float4 f;
        f.x = felu1(q.x); f.y = felu1(q.y); f.z = felu1(q.z); f.w = felu1(q.w);
        const int pc = (ltx * 4) ^ (((row >> 2) & 7) << 2);
        *(float4*)&Qs[row][pc] = f;
    }
    __syncthreads();

    const int rg = t >> 3;                 // 0..31 -> rows rg*4..rg*4+3
    const int mg = t & 7;                  // 0..7  -> cols mg*8..mg*8+7
    const int r0 = rg * 4, m0 = mg * 8;
    const int sw = ((rg & 7) << 2);

    float acc[4][8];
    float zz[4];
    #pragma unroll
    for (int r = 0; r < 4; ++r) {
        zz[r] = 0.0f;
        #pragma unroll
        for (int m = 0; m < 8; ++m) acc[r][m] = 0.0f;
    }

    #pragma unroll
    for (int d0 = 0; d0 < D_DIM; d0 += 4) {
        const float4 ks4 = *(const float4*)&Kss[d0];
        float4 qr[4];
        #pragma unroll
        for (int r = 0; r < 4; ++r) {
            qr[r] = *(const float4*)&Qs[r0 + r][d0 ^ sw];
            zz[r] += qr[r].x * ks4.x + qr[r].y * ks4.y
                   + qr[r].z * ks4.z + qr[r].w * ks4.w;
        }
        #pragma unroll
        for (int j = 0; j < 4; ++j) {
            const float4 kva = *(const float4*)&KVs[d0 + j][m0];
            const float4 kvb = *(const float4*)&KVs[d0 + j][m0 + 4];
            #pragma unroll
            for (int r = 0; r < 4; ++r) {
                const float q = (&qr[r].x)[j];
                acc[r][0] += q * kva.x; acc[r][1] += q * kva.y;
                acc[r][2] += q * kva.z; acc[r][3] += q * kva.w;
                acc[r][4] += q * kvb.x; acc[r][5] += q * kvb.y;
                acc[r][6] += q * kvb.z; acc[r][7] += q * kvb.w;
            }
        }
    }

    #pragma unroll
    for (int r = 0; r < 4; ++r) {
        const float z = 1.0f / (zz[r] + EPS);
        float4 o1, o2;
        o1.x = acc[r][0] * z; o1.y = acc[r][1] * z;
        o1.z = acc[r][2] * z; o1.w = acc[r][3] * z;
        o2.x = acc[r][4] * z; o2.y = acc[r][5] * z;
        o2.z = acc[r][6] * z; o2.w = acc[r][7] * z;
        float* op = Ob + (size_t)(sbase + r0 + r) * ROWSTRIDE + m0;
        *(float4*)op       = o1;
        *(float4*)(op + 4) = o2;
    }
}

extern "C" void kernel_launch(void* const* d_in, const int* in_sizes, int n_in,
                              void* d_out, int out_size, void* d_ws, size_t ws_size,
                              hipStream_t stream) {
    const float* q = (const float*)d_in[0];
    const float* k = (const float*)d_in[1];
    const float* v = (const float*)d_in[2];
    float* out = (float*)d_out;

    float* kvp  = (float*)d_ws;                                   // 33.6 MB
    float* ksp  = kvp + (size_t)NH * NCHUNK * D_DIM * D_DIM;      // 0.5 MB
    float* KVf  = ksp + (size_t)NH * NCHUNK * D_DIM;              // 1.05 MB
    float* Ksum = KVf + (size_t)NH * D_DIM * D_DIM;

    kv_partial_kernel<<<N_B * NCHUNK, 512, 0, stream>>>(k, v, kvp, ksp);
    kv_reduce_kernel<<<NH * 16, 256, 0, stream>>>(kvp, ksp, KVf, Ksum);
    out_kernel<<<NH * (S_LEN / 128), 256, 0, stream>>>(q, KVf, Ksum, out);
}

// Round 10
// 170.385 us; speedup vs baseline: 1.0237x; 1.0237x over previous
//
#include <hip/hip_runtime.h>
#include <math.h>

// LinearAttention: out[n,l,h,m] = (phi(Q[l])·KV[:,m]) / (phi(Q[l])·Ksum + eps)
//   KV[d][m] = sum_s phi(K[s,d]) V[s,m],  Ksum[d] = sum_s phi(K[s,d])
//   phi(x) = elu(x)+1 = x>0 ? x+1 : exp(x)

#define N_B 8
#define S_LEN 8192
#define H_N 8
#define D_DIM 64
#define NH (N_B * H_N)
#define EPS 1e-6f
#define ROWSTRIDE (H_N * D_DIM)   // 512 floats between consecutive s rows
#define NCHUNK 32
#define CROWS (S_LEN / NCHUNK)    // 256 s-rows per block
#define TS 64                     // s-rows per LDS tile
#define TILES (CROWS / TS)        // 4

typedef __attribute__((ext_vector_type(8)))  __bf16 bf16x8;
typedef __attribute__((ext_vector_type(4)))  float  f32x4;
typedef __attribute__((ext_vector_type(4)))  int    i32x4;

__device__ __forceinline__ float felu1(float x) {
    return x > 0.0f ? x + 1.0f : __expf(x);
}
__device__ __forceinline__ unsigned bfb(float f) {
    __bf16 h = (__bf16)f;                       // RNE convert
    return (unsigned)__builtin_bit_cast(unsigned short, h);
}
__device__ __forceinline__ int pack2bf(float a, float b) {
    return (int)(bfb(a) | (bfb(b) << 16));
}

// ---------------- Phase 1a: MFMA KV partial, occupancy-first ----------------
// 2048 blocks (8/CU queued, ~5 resident), 256 threads (4 waves), 32 KB LDS.
// Block = (n, c, h): 256 s-rows of ONE head. Column-gather staging (R7's
// proven coalesced pattern), plain RNE bf16 (validated R9), XOR-swizzled
// 128B LDS rows (R7: 0 conflicts). TS=64 tile = 2 K-steps of the
// mfma_f32_16x16x32_bf16. 2-deep register prefetch, 1 barrier/tile.
__global__ __launch_bounds__(256) void kv_partial_kernel(
        const float* __restrict__ Kin, const float* __restrict__ Vin,
        float* __restrict__ kvp,   // [NH*NCHUNK][64*64]
        float* __restrict__ ksp) { // [NH*NCHUNK][64]
    __shared__ __align__(16) unsigned int KT[2][64 * 32]; // 8 KB per buffer
    __shared__ __align__(16) unsigned int VT[2][64 * 32];

    const int b    = blockIdx.x;
    const int h_i  = b & 7;
    const int rest = b >> 3;
    const int c    = rest & (NCHUNK - 1);
    const int n_i  = rest >> 5;                 // NCHUNK = 32
    const int nh   = n_i * H_N + h_i;
    const int ob   = nh * NCHUNK + c;           // logical partial index
    const int s0   = c * CROWS;

    const int t = threadIdx.x;
    const int w = t >> 6;        // wave 0..3
    const int l = t & 63;        // lane
    const int d = l;             // staging column (d for K, m for V)

    const float* Kb = Kin + (size_t)n_i * S_LEN * ROWSTRIDE + (size_t)h_i * D_DIM;
    const float* Vb = Vin + (size_t)n_i * S_LEN * ROWSTRIDE + (size_t)h_i * D_DIM;

    float kraw[16], vraw[16];    // in-flight column gathers (16 s-rows, 1 col)
    float ksum = 0.0f;

    // wave w gathers s-octets w (rows w*8..+7) and w+4 (rows 32+w*8..+7)
    auto issue = [&](int tile) {
        const size_t base = (size_t)(s0 + tile * TS + w * 8) * ROWSTRIDE + d;
        #pragma unroll
        for (int e = 0; e < 8; ++e) {
            kraw[e] = Kb[base + (size_t)e * ROWSTRIDE];
            vraw[e] = Vb[base + (size_t)e * ROWSTRIDE];
        }
        #pragma unroll
        for (int e = 0; e < 8; ++e) {
            kraw[8 + e] = Kb[base + (size_t)(32 + e) * ROWSTRIDE];
            vraw[8 + e] = Vb[base + (size_t)(32 + e) * ROWSTRIDE];
        }
    };

    // phi (K only) + RNE bf16 pack + swizzled LDS write; ksum in fp32
    auto convwrite = [&](int buf) {
        int kp[8], vp[8];
        #pragma unroll
        for (int p = 0; p < 4; ++p) {
            const float a0 = felu1(kraw[2 * p]);
            const float a1 = felu1(kraw[2 * p + 1]);
            const float b0 = felu1(kraw[8 + 2 * p]);
            const float b1 = felu1(kraw[8 + 2 * p + 1]);
            ksum += (a0 + a1) + (b0 + b1);
            kp[p]     = pack2bf(a0, a1);
            kp[4 + p] = pack2bf(b0, b1);
            vp[p]     = pack2bf(vraw[2 * p],     vraw[2 * p + 1]);
            vp[4 + p] = pack2bf(vraw[8 + 2 * p], vraw[8 + 2 * p + 1]);
        }
        const int gA = ((w)     ^ (d & 7)) * 4;   // octet w
        const int gB = ((w + 4) ^ (d & 7)) * 4;   // octet w+4
        unsigned int* kr = &KT[buf][d * 32];
        unsigned int* vr = &VT[buf][d * 32];
        *(i32x4*)&kr[gA] = (i32x4){kp[0], kp[1], kp[2], kp[3]};
        *(i32x4*)&kr[gB] = (i32x4){kp[4], kp[5], kp[6], kp[7]};
        *(i32x4*)&vr[gA] = (i32x4){vp[0], vp[1], vp[2], vp[3]};
        *(i32x4*)&vr[gB] = (i32x4){vp[4], vp[5], vp[6], vp[7]};
    };

    f32x4 acc[4];
    #pragma unroll
    for (int i = 0; i < 4; ++i) acc[i] = (f32x4){0.f, 0.f, 0.f, 0.f};

    // fragment offsets (dword units): row*32 + physgroup*4
    const int arow = 16 * w + (l & 15);               // A row = d (wave slab)
    const int g0   = (((l >> 4))     ^ (l & 7)) * 4;  // k-step 0 octets 0..3
    const int g1   = ((4 + (l >> 4)) ^ (l & 7)) * 4;  // k-step 1 octets 4..7
    const int brow = (l & 15);

    auto compute = [&](int buf) {
        const bf16x8 A0 = __builtin_bit_cast(bf16x8, *(const i32x4*)&KT[buf][arow * 32 + g0]);
        const bf16x8 A1 = __builtin_bit_cast(bf16x8, *(const i32x4*)&KT[buf][arow * 32 + g1]);
        #pragma unroll
        for (int mt = 0; mt < 4; ++mt) {
            const int br = (16 * mt + brow) * 32;
            const bf16x8 B0 = __builtin_bit_cast(bf16x8, *(const i32x4*)&VT[buf][br + g0]);
            const bf16x8 B1 = __builtin_bit_cast(bf16x8, *(const i32x4*)&VT[buf][br + g1]);
            acc[mt] = __builtin_amdgcn_mfma_f32_16x16x32_bf16(A0, B0, acc[mt], 0, 0, 0);
            acc[mt] = __builtin_amdgcn_mfma_f32_16x16x32_bf16(A1, B1, acc[mt], 0, 0, 0);
        }
    };

    // 2-deep pipeline: stage 0, prefetch 1; per tile {compute, conv t+1, issue t+2}
    issue(0);
    convwrite(0);
    issue(1);
    __syncthreads();

    for (int tile = 0; tile < TILES; ++tile) {
        const int cur = tile & 1;
        compute(cur);
        if (tile + 1 < TILES) convwrite(cur ^ 1);
        if (tile + 2 < TILES) issue(tile + 2);
        __syncthreads();
    }

    // ---- write partial KV: D[row][col], col = l&15, row = (l>>4)*4 + reg ----
    float* kvo = kvp + (size_t)ob * (D_DIM * D_DIM);
    #pragma unroll
    for (int mt = 0; mt < 4; ++mt) {
        #pragma unroll
        for (int r = 0; r < 4; ++r) {
            const int row = 16 * w + (l >> 4) * 4 + r;   // d
            const int col = 16 * mt + (l & 15);          // m
            kvo[row * 64 + col] = acc[mt][r];
        }
    }

    // ---- ksum: per-thread column partial -> LDS reduce over 4 waves ----
    float* ksl = (float*)&KT[0][0];
    ksl[w * 64 + d] = ksum;        // all waves past final barrier
    __syncthreads();
    if (t < D_DIM) {
        ksp[(size_t)ob * D_DIM + t] =
            ksl[t] + ksl[64 + t] + ksl[128 + t] + ksl[192 + t];
    }
}

// ---------------- Phase 1b: reduce partials -> final KV, Ksum ----------------
__global__ __launch_bounds__(256) void kv_reduce_kernel(
        const float* __restrict__ kvp, const float* __restrict__ ksp,
        float* __restrict__ KV, float* __restrict__ Ksum) {
    const int nh = blockIdx.x >> 4;
    const int eb = blockIdx.x & 15;
    const int t  = threadIdx.x;
    const int e  = eb * 256 + t;
    float s = 0.0f;
    const float* base = kvp + (size_t)nh * NCHUNK * (D_DIM * D_DIM) + e;
    #pragma unroll 8
    for (int c = 0; c < NCHUNK; ++c)
        s += base[(size_t)c * (D_DIM * D_DIM)];
    KV[(size_t)nh * (D_DIM * D_DIM) + e] = s;
    if (eb == 0 && t < D_DIM) {
        float ks = 0.0f;
        #pragma unroll 8
        for (int c = 0; c < NCHUNK; ++c)
            ks += ksp[(size_t)nh * NCHUNK * D_DIM + (size_t)c * D_DIM + t];
        Ksum[(size_t)nh * D_DIM + t] = ks;
    }
}

// ---------------- Phase 2: out = (Q·KV) / (Q·Ksum + eps) ----------------
// Grid remap: b = ((n*nblk + rb) * 8) + h (R8, kept — 6.4 TB/s measured).
__global__ __launch_bounds__(256) void out_kernel(
        const float* __restrict__ Qin, const float* __restrict__ KV,
        const float* __restrict__ Ksum, float* __restrict__ Out) {
    constexpr int RPB  = 128;
    constexpr int QPAD = 68;
    __shared__ __align__(16) float KVs[D_DIM][D_DIM];   // 16 KB
    __shared__ __align__(16) float Kss[D_DIM];
    __shared__ __align__(16) float Qs[RPB][QPAD];       // 34.8 KB, XOR-swizzled cols

    const int b    = blockIdx.x;
    const int nblk = S_LEN / RPB;          // 64
    const int h_i  = b & 7;
    const int rest = b >> 3;
    const int rb   = rest & (nblk - 1);
    const int n_i  = rest >> 6;            // nblk = 64
    const int nh   = n_i * H_N + h_i;
    const int t    = threadIdx.x;

    const float* Qb = Qin + (size_t)n_i * S_LEN * ROWSTRIDE + (size_t)h_i * D_DIM;
    float*       Ob = Out + (size_t)n_i * S_LEN * ROWSTRIDE + (size_t)h_i * D_DIM;

    {
        const float4* src = (const float4*)(KV + (size_t)nh * (D_DIM * D_DIM));
        float4* dst = (float4*)(&KVs[0][0]);
        #pragma unroll
        for (int i = 0; i < 4; ++i) dst[t + 256 * i] = src[t + 256 * i];
        if (t < 16) ((float4*)Kss)[t] = ((const float4*)(Ksum + (size_t)nh * D_DIM))[t];
    }

    const int ltx = t & 15, lty = t >> 4;
    const int sbase = rb * RPB;
    #pragma unroll
    for (int i = 0; i < 8; ++i) {
        const int row = lty + 16 * i;
        const float4 q = *(const float4*)(Qb + (size_t)(sbase + row) * ROWSTRIDE + ltx * 4);
        float4 f;
        f.x = felu1(q.x); f.y = felu1(q.y); f.z = felu1(q.z); f.w = felu1(q.w);
        const int pc = (ltx * 4) ^ (((row >> 2) & 7) << 2);
        *(float4*)&Qs[row][pc] = f;
    }
    __syncthreads();

    const int rg = t >> 3;                 // 0..31 -> rows rg*4..rg*4+3
    const int mg = t & 7;                  // 0..7  -> cols mg*8..mg*8+7
    const int r0 = rg * 4, m0 = mg * 8;
    const int sw = ((rg & 7) << 2);

    float acc[4][8];
    float zz[4];
    #pragma unroll
    for (int r = 0; r < 4; ++r) {
        zz[r] = 0.0f;
        #pragma unroll
        for (int m = 0; m < 8; ++m) acc[r][m] = 0.0f;
    }

    #pragma unroll
    for (int d0 = 0; d0 < D_DIM; d0 += 4) {
        const float4 ks4 = *(const float4*)&Kss[d0];
        float4 qr[4];
        #pragma unroll
        for (int r = 0; r < 4; ++r) {
            qr[r] = *(const float4*)&Qs[r0 + r][d0 ^ sw];
            zz[r] += qr[r].x * ks4.x + qr[r].y * ks4.y
                   + qr[r].z * ks4.z + qr[r].w * ks4.w;
        }
        #pragma unroll
        for (int j = 0; j < 4; ++j) {
            const float4 kva = *(const float4*)&KVs[d0 + j][m0];
            const float4 kvb = *(const float4*)&KVs[d0 + j][m0 + 4];
            #pragma unroll
            for (int r = 0; r < 4; ++r) {
                const float q = (&qr[r].x)[j];
                acc[r][0] += q * kva.x; acc[r][1] += q * kva.y;
                acc[r][2] += q * kva.z; acc[r][3] += q * kva.w;
                acc[r][4] += q * kvb.x; acc[r][5] += q * kvb.y;
                acc[r][6] += q * kvb.z; acc[r][7] += q * kvb.w;
            }
        }
    }

    #pragma unroll
    for (int r = 0; r < 4; ++r) {
        const float z = 1.0f / (zz[r] + EPS);
        float4 o1, o2;
        o1.x = acc[r][0] * z; o1.y = acc[r][1] * z;
        o1.z = acc[r][2] * z; o1.w = acc[r][3] * z;
        o2.x = acc[r][4] * z; o2.y = acc[r][5] * z;
        o2.z = acc[r][6] * z; o2.w = acc[r][7] * z;
        float* op = Ob + (size_t)(sbase + r0 + r) * ROWSTRIDE + m0;
        *(float4*)op       = o1;
        *(float4*)(op + 4) = o2;
    }
}

extern "C" void kernel_launch(void* const* d_in, const int* in_sizes, int n_in,
                              void* d_out, int out_size, void* d_ws, size_t ws_size,
                              hipStream_t stream) {
    const float* q = (const float*)d_in[0];
    const float* k = (const float*)d_in[1];
    const float* v = (const float*)d_in[2];
    float* out = (float*)d_out;

    float* kvp  = (float*)d_ws;                                   // 33.6 MB
    float* ksp  = kvp + (size_t)NH * NCHUNK * D_DIM * D_DIM;      // 0.5 MB
    float* KVf  = ksp + (size_t)NH * NCHUNK * D_DIM;              // 1.05 MB
    float* Ksum = KVf + (size_t)NH * D_DIM * D_DIM;

    kv_partial_kernel<<<N_B * NCHUNK * H_N, 256, 0, stream>>>(k, v, kvp, ksp);
    kv_reduce_kernel<<<NH * 16, 256, 0, stream>>>(kvp, ksp, KVf, Ksum);
    out_kernel<<<NH * (S_LEN / 128), 256, 0, stream>>>(q, KVf, Ksum, out);
}